// Round 1
// baseline (1415.311 us; speedup 1.0000x reference)
//
#include <hip/hip_runtime.h>

namespace {

constexpr int T_STEPS = 4096;
constexpr int NBATCH  = 2048;
constexpr int HID     = 10;

__device__ __forceinline__ float ex2(float x){ return __builtin_amdgcn_exp2f(x); }
__device__ __forceinline__ float rcp_(float x){ return __builtin_amdgcn_rcpf(x); }
// sigmoid(x) = 1/(1+exp(-x)) = rcp(1 + 2^(-x*log2e))
__device__ __forceinline__ float sigm(float x){ return rcp_(1.0f + ex2(x * -1.4426950408889634f)); }
// tanh(x) = 1 - 2/(1 + e^(2x)) = 1 - 2*rcp(1 + 2^(x*2*log2e))
__device__ __forceinline__ float tanh_(float x){ return 1.0f - 2.0f*rcp_(1.0f + ex2(x * 2.8853901617779268f)); }

template<int IMM>
__device__ __forceinline__ float swz(float v){
    return __int_as_float(__builtin_amdgcn_ds_swizzle(__float_as_int(v), IMM));
}

// ds_swizzle BitMode: src_lane(within 32-row) = ((lane & AND) | OR) ^ XOR ; imm = (XOR<<10)|(OR<<5)|AND
// Broadcast of lane j to all 32 lanes of the row: AND=0, OR=j  -> imm = j<<5

// A[j] <- lane j (layer-0 half, h=j), Bv[j] <- lane 16+j (layer-1 half, h=j)
__device__ __forceinline__ void bcast_h(float (&A)[HID], float (&Bv)[HID], float hn){
    A[0]=swz<(0<<5)>(hn);   A[1]=swz<(1<<5)>(hn);   A[2]=swz<(2<<5)>(hn);   A[3]=swz<(3<<5)>(hn);   A[4]=swz<(4<<5)>(hn);
    A[5]=swz<(5<<5)>(hn);   A[6]=swz<(6<<5)>(hn);   A[7]=swz<(7<<5)>(hn);   A[8]=swz<(8<<5)>(hn);   A[9]=swz<(9<<5)>(hn);
    Bv[0]=swz<(16<<5)>(hn); Bv[1]=swz<(17<<5)>(hn); Bv[2]=swz<(18<<5)>(hn); Bv[3]=swz<(19<<5)>(hn); Bv[4]=swz<(20<<5)>(hn);
    Bv[5]=swz<(21<<5)>(hn); Bv[6]=swz<(22<<5)>(hn); Bv[7]=swz<(23<<5)>(hn); Bv[8]=swz<(24<<5)>(hn); Bv[9]=swz<(25<<5)>(hn);
}

// xs[jj] <- lane jj of the row (lane jj holds x[t = 8*i + jj] for this row's batch)
__device__ __forceinline__ void xsplat(float (&xs)[8], float xpre){
    xs[0]=swz<(0<<5)>(xpre); xs[1]=swz<(1<<5)>(xpre); xs[2]=swz<(2<<5)>(xpre); xs[3]=swz<(3<<5)>(xpre);
    xs[4]=swz<(4<<5)>(xpre); xs[5]=swz<(5<<5)>(xpre); xs[6]=swz<(6<<5)>(xpre); xs[7]=swz<(7<<5)>(xpre);
}

// One unified wave-step s: lanes 0-15 of each 32-row compute layer-0 step t=s,
// lanes 16-31 compute layer-1 step t=s-1 (skewed).  A = h0rep (h0[s-1] on entry),
// Bv = h1rep (h1[s-2] on entry); Wb[g][0]*x encodes layer-0's scalar input.
__device__ __forceinline__ void lstm_step(
    const float (&Wa)[4][HID], const float (&Wb)[4][HID],
    float b0, float b1, float b2, float b3,
    float (&A)[HID], float (&Bv)[HID],
    float &c, float xv, bool isL0,
    float wlin, float blin, int t_l1, float* __restrict__ out, int b)
{
    float a0=b0, a1=b1, a2=b2, a3=b3;
    #pragma unroll
    for (int j=0;j<HID;++j){
        a0 = fmaf(Wa[0][j], A[j], a0);
        a1 = fmaf(Wa[1][j], A[j], a1);
        a2 = fmaf(Wa[2][j], A[j], a2);
        a3 = fmaf(Wa[3][j], A[j], a3);
    }
    const float B0u = isL0 ? xv : Bv[0];   // L0: x input via Wb column 0; L1: h1rep[0]
    a0 = fmaf(Wb[0][0], B0u, a0);
    a1 = fmaf(Wb[1][0], B0u, a1);
    a2 = fmaf(Wb[2][0], B0u, a2);
    a3 = fmaf(Wb[3][0], B0u, a3);
    #pragma unroll
    for (int j=1;j<HID;++j){
        a0 = fmaf(Wb[0][j], Bv[j], a0);
        a1 = fmaf(Wb[1][j], Bv[j], a1);
        a2 = fmaf(Wb[2][j], Bv[j], a2);
        a3 = fmaf(Wb[3][j], Bv[j], a3);
    }
    const float ig = sigm(a0);
    const float fg = sigm(a1);
    const float gg = tanh_(a2);
    const float og = sigm(a3);
    c = fmaf(fg, c, ig*gg);
    const float hn = og * tanh_(c);
    bcast_h(A, Bv, hn);
    if (t_l1 >= T_STEPS-2) {               // uniform branch: true only at s=4095,4096
        float p = hn * wlin;               // wlin==0 on L0 half and pad lanes
        p += swz<((1<<10)|31)>(p);
        p += swz<((2<<10)|31)>(p);
        p += swz<((4<<10)|31)>(p);
        p += swz<((8<<10)|31)>(p);
        p += swz<((16<<10)|31)>(p);
        if ((threadIdx.x & 31) == 0)
            out[(t_l1 - (T_STEPS-2))*NBATCH + b] = p + blin;
    }
}

__global__ __launch_bounds__(64) void lstm2_kernel(
    const float* __restrict__ x,
    const float* __restrict__ Wih0, const float* __restrict__ Whh0,
    const float* __restrict__ bih0, const float* __restrict__ bhh0,
    const float* __restrict__ Wih1, const float* __restrict__ Whh1,
    const float* __restrict__ bih1, const float* __restrict__ bhh1,
    const float* __restrict__ Wlin, const float* __restrict__ blin_p,
    float* __restrict__ out)
{
    const int tid = (int)threadIdx.x;                  // 0..63, two 32-lane batch groups
    const int b   = ((int)blockIdx.x * 64 + tid) >> 5; // batch index 0..2047
    const int hl  = tid & 15;                          // hidden index (padded 10..15)
    const bool isL0 = (tid & 16) == 0;                 // lanes 0-15 / 32-47: layer 0
    const int he  = hl < HID ? hl : HID-1;
    const float wm = hl < HID ? 1.0f : 0.0f;           // pad lanes: zero weights -> h=c=0 forever

    float Wa[4][HID], Wb[4][HID], bs[4];
    if (isL0) {
        #pragma unroll
        for (int g=0; g<4; ++g){
            const int r = g*HID + he;                  // torch gate order i,f,g,o
            #pragma unroll
            for (int j=0;j<HID;++j) Wa[g][j] = Whh0[r*HID+j]*wm;
            #pragma unroll
            for (int j=0;j<HID;++j) Wb[g][j] = 0.0f;
            Wb[g][0] = Wih0[r]*wm;                     // W_ih0 is (40,1)
            bs[g] = (bih0[r]+bhh0[r])*wm;
        }
    } else {
        #pragma unroll
        for (int g=0; g<4; ++g){
            const int r = g*HID + he;
            #pragma unroll
            for (int j=0;j<HID;++j) Wa[g][j] = Wih1[r*HID+j]*wm;   // multiplies h0rep
            #pragma unroll
            for (int j=0;j<HID;++j) Wb[g][j] = Whh1[r*HID+j]*wm;   // multiplies h1rep
            bs[g] = (bih1[r]+bhh1[r])*wm;
        }
    }
    const float wlin = isL0 ? 0.0f : Wlin[he]*wm;
    const float blin = blin_p[0];

    float A[HID], Bv[HID];
    #pragma unroll
    for (int j=0;j<HID;++j){ A[j]=0.0f; Bv[j]=0.0f; }
    float c = 0.0f;

    // x prefetch: lane (tid&7) of each row holds x[8*i + (tid&7)] for this row's batch
    const float* xp = x + (size_t)(tid & 7) * NBATCH + b;
    float xpre = xp[0];
    float xs[8];

    // ---- peeled iteration 0 (s = 0..7); L1 half gets zeroed bias at s=0 so its
    //      fake t=-1 step yields h=c=0 exactly (i=f=o=0.5, g=0, c_in=0).
    xsplat(xs, xpre);
    xpre = xp[(size_t)8 * NBATCH];
    lstm_step(Wa,Wb, isL0?bs[0]:0.0f, isL0?bs[1]:0.0f, isL0?bs[2]:0.0f, isL0?bs[3]:0.0f,
              A,Bv,c, xs[0], isL0, wlin, blin, -1, out, b);
    lstm_step(Wa,Wb, bs[0],bs[1],bs[2],bs[3], A,Bv,c, xs[1], isL0, wlin, blin, 0, out, b);
    lstm_step(Wa,Wb, bs[0],bs[1],bs[2],bs[3], A,Bv,c, xs[2], isL0, wlin, blin, 1, out, b);
    lstm_step(Wa,Wb, bs[0],bs[1],bs[2],bs[3], A,Bv,c, xs[3], isL0, wlin, blin, 2, out, b);
    lstm_step(Wa,Wb, bs[0],bs[1],bs[2],bs[3], A,Bv,c, xs[4], isL0, wlin, blin, 3, out, b);
    lstm_step(Wa,Wb, bs[0],bs[1],bs[2],bs[3], A,Bv,c, xs[5], isL0, wlin, blin, 4, out, b);
    lstm_step(Wa,Wb, bs[0],bs[1],bs[2],bs[3], A,Bv,c, xs[6], isL0, wlin, blin, 5, out, b);
    lstm_step(Wa,Wb, bs[0],bs[1],bs[2],bs[3], A,Bv,c, xs[7], isL0, wlin, blin, 6, out, b);

    // ---- main loop: iterations 1..511 (s = 8..4095)
    for (int i=1; i<512; ++i){
        xsplat(xs, xpre);
        if (i < 511) xpre = xp[(size_t)(i+1)*8*NBATCH];   // prefetch next 8 timesteps
        const int s0 = i*8;
        #pragma unroll
        for (int jj=0; jj<8; ++jj){
            lstm_step(Wa,Wb, bs[0],bs[1],bs[2],bs[3], A,Bv,c, xs[jj],
                      isL0, wlin, blin, s0+jj-1, out, b);
        }
    }

    // ---- epilogue wave-step s=4096: L1 computes t=4095 (L0 half computes unused junk, x=0)
    lstm_step(Wa,Wb, bs[0],bs[1],bs[2],bs[3], A,Bv,c, 0.0f, isL0, wlin, blin, T_STEPS-1, out, b);
}

} // anonymous namespace

extern "C" void kernel_launch(void* const* d_in, const int* in_sizes, int n_in,
                              void* d_out, int out_size, void* d_ws, size_t ws_size,
                              hipStream_t stream) {
    const float* x    = (const float*)d_in[0];
    const float* Wih0 = (const float*)d_in[1];
    const float* Whh0 = (const float*)d_in[2];
    const float* bih0 = (const float*)d_in[3];
    const float* bhh0 = (const float*)d_in[4];
    const float* Wih1 = (const float*)d_in[5];
    const float* Whh1 = (const float*)d_in[6];
    const float* bih1 = (const float*)d_in[7];
    const float* bhh1 = (const float*)d_in[8];
    const float* Wlin = (const float*)d_in[9];
    const float* blin = (const float*)d_in[10];
    float* out = (float*)d_out;

    // 2048 batches x 32 lanes = 65536 threads; 64-thread blocks -> 1024 waves (1/SIMD chip-wide)
    hipLaunchKernelGGL(lstm2_kernel, dim3(2048*32/64), dim3(64), 0, stream,
                       x, Wih0, Whh0, bih0, bhh0, Wih1, Whh1, bih1, bhh1, Wlin, blin, out);
}

// Round 3
// 1042.808 us; speedup vs baseline: 1.3572x; 1.3572x over previous
//
#include <hip/hip_runtime.h>

namespace {

constexpr int T_STEPS = 4096;
constexpr int NBATCH  = 2048;
constexpr int HID     = 10;

__device__ __forceinline__ float ex2(float x){ return __builtin_amdgcn_exp2f(x); }
__device__ __forceinline__ float rcp_(float x){ return __builtin_amdgcn_rcpf(x); }
// sigmoid(x) = rcp(1 + 2^(-x*log2e)) ; tanh(x) = 1 - 2*rcp(1 + 2^(x*2*log2e))
__device__ __forceinline__ float sigm(float x){ return rcp_(1.0f + ex2(x * -1.4426950408889634f)); }
__device__ __forceinline__ float tanh_(float x){ return 1.0f - 2.0f*rcp_(1.0f + ex2(x * 2.8853901617779268f)); }

template<int IMM>
__device__ __forceinline__ float swz(float v){
    return __int_as_float(__builtin_amdgcn_ds_swizzle(__float_as_int(v), IMM));
}
__device__ __forceinline__ float bperm(int addr, float v){
    return __int_as_float(__builtin_amdgcn_ds_bpermute(addr, __float_as_int(v)));
}
// VALU cross-lane: lane i <- lane i+4 within its 16-lane DPP row.
// NOTE: that is row_shl:4 = ctrl 0x104 (row_shr:4=0x114 is lane i <- lane i-4 —
// the R2 bug). bound_ctrl=true: cross-row sources read 0.
__device__ __forceinline__ float dpp_pull4(float v){
    return __int_as_float(__builtin_amdgcn_update_dpp(0, __float_as_int(v), 0x104, 0xF, 0xF, true));
}

// Lane roles within each 32-lane row (rr = lane & 31):
//   L0  = {0..7,10,11}     h = rr<8 ? rr : rr-2      owns h0[h], full L0 gates (x + 10 h0-MACs)
//   L1A = {8,9,16..19,24..27} h per map below         h0-part of L1 gates (10 MACs), owns h1[h] after combine
//   L1B = L1A + 4 = {12,13,20..23,28..31}             h1-part of L1 gates (10 MACs)
//   pad = {14,15}                                     zero weights
// Combine: L1A lane i pulls partner partial from lane i+4 via dpp row_shl:4 (same 16-lane row for all pairs).
// Skew: at wave-step s, L0 computes t=s, L1 computes t=s-1.

__device__ __forceinline__ void lstm_step(
    const float (&Wv)[4][HID], const float (&Wx)[4],
    float b0, float b1, float b2, float b3,
    const int (&addrV)[HID],
    float &hn, float &c, float xv, float selA,
    float wlin, float blin, int t_l1, float* __restrict__ out, int b)
{
    // operand fetch: V[j] = h0[j] (L0, L1A lanes) or h1[j] (L1B lanes), per-lane idx
    float V[HID];
    #pragma unroll
    for (int j=0;j<HID;++j) V[j] = bperm(addrV[j], hn);

    float a0=b0, a1=b1, a2=b2, a3=b3;
    #pragma unroll
    for (int j=0;j<HID;++j){
        a0 = fmaf(Wv[0][j], V[j], a0);
        a1 = fmaf(Wv[1][j], V[j], a1);
        a2 = fmaf(Wv[2][j], V[j], a2);
        a3 = fmaf(Wv[3][j], V[j], a3);
    }
    a0 = fmaf(Wx[0], xv, a0);
    a1 = fmaf(Wx[1], xv, a1);
    a2 = fmaf(Wx[2], xv, a2);
    a3 = fmaf(Wx[3], xv, a3);

    // combine L1 halves: L1A += partner(L1B) partial; others add 0 (selA=0)
    a0 = fmaf(selA, dpp_pull4(a0), a0);
    a1 = fmaf(selA, dpp_pull4(a1), a1);
    a2 = fmaf(selA, dpp_pull4(a2), a2);
    a3 = fmaf(selA, dpp_pull4(a3), a3);

    const float ig = sigm(a0);
    const float fg = sigm(a1);
    const float gg = tanh_(a2);
    const float og = sigm(a3);
    c  = fmaf(fg, c, ig*gg);
    hn = og * tanh_(c);

    if (t_l1 >= T_STEPS-2) {               // uniform branch: true only at s=4095,4096
        float p = hn * wlin;               // wlin!=0 only on L1A lanes
        p += swz<((1<<10)|31)>(p);
        p += swz<((2<<10)|31)>(p);
        p += swz<((4<<10)|31)>(p);
        p += swz<((8<<10)|31)>(p);
        p += swz<((16<<10)|31)>(p);
        if ((threadIdx.x & 31) == 0)
            out[(t_l1 - (T_STEPS-2))*NBATCH + b] = p + blin;
    }
}

// xs[jj] <- lane jj of the row (lane jj holds x[t = 8*i + jj] for this row's batch)
__device__ __forceinline__ void xsplat(float (&xs)[8], float xpre){
    xs[0]=swz<(0<<5)>(xpre); xs[1]=swz<(1<<5)>(xpre); xs[2]=swz<(2<<5)>(xpre); xs[3]=swz<(3<<5)>(xpre);
    xs[4]=swz<(4<<5)>(xpre); xs[5]=swz<(5<<5)>(xpre); xs[6]=swz<(6<<5)>(xpre); xs[7]=swz<(7<<5)>(xpre);
}

__global__ __launch_bounds__(64) void lstm2_kernel(
    const float* __restrict__ x,
    const float* __restrict__ Wih0, const float* __restrict__ Whh0,
    const float* __restrict__ bih0, const float* __restrict__ bhh0,
    const float* __restrict__ Wih1, const float* __restrict__ Whh1,
    const float* __restrict__ bih1, const float* __restrict__ bhh1,
    const float* __restrict__ Wlin, const float* __restrict__ blin_p,
    float* __restrict__ out)
{
    const int tid = (int)threadIdx.x;                  // 0..63, two 32-lane rows
    const int rr  = tid & 31;
    const int rowbase = tid & 32;
    const int b   = ((int)blockIdx.x * 64 + tid) >> 5; // batch index 0..2047

    const bool isL0  = (rr<8) || rr==10 || rr==11;
    const bool isL1A = rr==8 || rr==9 || (rr>=16&&rr<=19) || (rr>=24&&rr<=27);
    const bool isL1B = rr==12 || rr==13 || (rr>=20&&rr<=23) || (rr>=28&&rr<=31);

    int h = 0;
    if (isL0)       h = (rr<8) ? rr : rr-2;
    else if (isL1A) h = (rr==8||rr==9) ? rr : ((rr<20) ? rr-16 : rr-20);
    else if (isL1B){ const int p = rr-4; h = (p==8||p==9) ? p : ((p<20) ? p-16 : p-20); }

    // per-lane operand source lanes: slot j reads h0[j] (L0/L1A/pad) or h1[j] (L1B)
    int addrV[HID];
    #pragma unroll
    for (int j=0;j<HID;++j){
        const int l0l = (j<8) ? j : j+2;                        // lane owning h0[j]
        const int l1l = (j<4) ? 16+j : ((j<8) ? 20+j : j);      // lane owning h1[j] (L1A set)
        addrV[j] = (rowbase + (isL1B ? l1l : l0l)) * 4;
    }

    float Wv[4][HID], Wx[4], bs[4];
    #pragma unroll
    for (int g=0; g<4; ++g){
        const int r = g*HID + h;                                // torch gate order i,f,g,o
        if (isL0){
            #pragma unroll
            for (int j=0;j<HID;++j) Wv[g][j] = Whh0[r*HID+j];
            Wx[g] = Wih0[r];                                    // W_ih0 is (40,1)
            bs[g] = bih0[r]+bhh0[r];
        } else if (isL1A){
            #pragma unroll
            for (int j=0;j<HID;++j) Wv[g][j] = Wih1[r*HID+j];   // multiplies h0
            Wx[g] = 0.0f;
            bs[g] = bih1[r]+bhh1[r];
        } else if (isL1B){
            #pragma unroll
            for (int j=0;j<HID;++j) Wv[g][j] = Whh1[r*HID+j];   // multiplies h1
            Wx[g] = 0.0f;
            bs[g] = 0.0f;                                       // bias lives on L1A
        } else {
            #pragma unroll
            for (int j=0;j<HID;++j) Wv[g][j] = 0.0f;
            Wx[g] = 0.0f; bs[g] = 0.0f;
        }
    }
    const float selA = isL1A ? 1.0f : 0.0f;
    const float wlin = isL1A ? Wlin[h] : 0.0f;
    const float blin = blin_p[0];

    float hn = 0.0f, c = 0.0f;

    // x prefetch: lane (rr&7) of each row holds x[8*i + (rr&7)] for this row's batch
    const float* xp = x + (size_t)(tid & 7) * NBATCH + b;
    float xpre = xp[0];
    float xs[8];

    // ---- peeled iteration 0 (s = 0..7); L1 gets zero bias at s=0 so its fake
    //      t=-1 step yields h=c=0 exactly (a=0 -> i=f=o=0.5, g=0, c_in=0).
    xsplat(xs, xpre);
    xpre = xp[(size_t)8 * NBATCH];
    lstm_step(Wv,Wx, isL0?bs[0]:0.0f, isL0?bs[1]:0.0f, isL0?bs[2]:0.0f, isL0?bs[3]:0.0f,
              addrV, hn,c, xs[0], selA, wlin, blin, -1, out, b);
    lstm_step(Wv,Wx, bs[0],bs[1],bs[2],bs[3], addrV, hn,c, xs[1], selA, wlin, blin, 0, out, b);
    lstm_step(Wv,Wx, bs[0],bs[1],bs[2],bs[3], addrV, hn,c, xs[2], selA, wlin, blin, 1, out, b);
    lstm_step(Wv,Wx, bs[0],bs[1],bs[2],bs[3], addrV, hn,c, xs[3], selA, wlin, blin, 2, out, b);
    lstm_step(Wv,Wx, bs[0],bs[1],bs[2],bs[3], addrV, hn,c, xs[4], selA, wlin, blin, 3, out, b);
    lstm_step(Wv,Wx, bs[0],bs[1],bs[2],bs[3], addrV, hn,c, xs[5], selA, wlin, blin, 4, out, b);
    lstm_step(Wv,Wx, bs[0],bs[1],bs[2],bs[3], addrV, hn,c, xs[6], selA, wlin, blin, 5, out, b);
    lstm_step(Wv,Wx, bs[0],bs[1],bs[2],bs[3], addrV, hn,c, xs[7], selA, wlin, blin, 6, out, b);

    // ---- main loop: iterations 1..511 (s = 8..4095)
    for (int i=1; i<512; ++i){
        xsplat(xs, xpre);
        if (i < 511) xpre = xp[(size_t)(i+1)*8*NBATCH];   // prefetch next 8 timesteps
        const int s0 = i*8;
        #pragma unroll
        for (int jj=0; jj<8; ++jj){
            lstm_step(Wv,Wx, bs[0],bs[1],bs[2],bs[3], addrV, hn,c, xs[jj],
                      selA, wlin, blin, s0+jj-1, out, b);
        }
    }

    // ---- epilogue wave-step s=4096: L1 computes t=4095 (L0 half computes unused junk, x=0)
    lstm_step(Wv,Wx, bs[0],bs[1],bs[2],bs[3], addrV, hn,c, 0.0f, selA, wlin, blin, T_STEPS-1, out, b);
}

} // anonymous namespace

extern "C" void kernel_launch(void* const* d_in, const int* in_sizes, int n_in,
                              void* d_out, int out_size, void* d_ws, size_t ws_size,
                              hipStream_t stream) {
    const float* x    = (const float*)d_in[0];
    const float* Wih0 = (const float*)d_in[1];
    const float* Whh0 = (const float*)d_in[2];
    const float* bih0 = (const float*)d_in[3];
    const float* bhh0 = (const float*)d_in[4];
    const float* Wih1 = (const float*)d_in[5];
    const float* Whh1 = (const float*)d_in[6];
    const float* bih1 = (const float*)d_in[7];
    const float* bhh1 = (const float*)d_in[8];
    const float* Wlin = (const float*)d_in[9];
    const float* blin = (const float*)d_in[10];
    float* out = (float*)d_out;

    // 2048 batches x 32 lanes = 65536 threads; 64-thread blocks -> 1024 waves (1/SIMD chip-wide)
    hipLaunchKernelGGL(lstm2_kernel, dim3(2048*32/64), dim3(64), 0, stream,
                       x, Wih0, Whh0, bih0, bhh0, Wih1, Whh1, bih1, bhh1, Wlin, blin, out);
}

// Round 6
// 820.650 us; speedup vs baseline: 1.7246x; 1.2707x over previous
//
#include <hip/hip_runtime.h>

namespace {

constexpr int T_STEPS = 4096;
constexpr int NBATCH  = 2048;
constexpr int HID     = 10;

typedef float v2f __attribute__((ext_vector_type(2)));

__device__ __forceinline__ float ex2(float x){ return __builtin_amdgcn_exp2f(x); }
__device__ __forceinline__ float rcp_(float x){ return __builtin_amdgcn_rcpf(x); }
// sigmoid(x) = rcp(1 + 2^(-x*log2e)) ; tanh(x) = 1 - 2*rcp(1 + 2^(x*2*log2e))
__device__ __forceinline__ float sigm(float x){ return rcp_(1.0f + ex2(x * -1.4426950408889634f)); }
__device__ __forceinline__ float tanh_(float x){ return 1.0f - 2.0f*rcp_(1.0f + ex2(x * 2.8853901617779268f)); }

template<int IMM>
__device__ __forceinline__ float swz(float v){
    return __int_as_float(__builtin_amdgcn_ds_swizzle(__float_as_int(v), IMM));
}
// VALU cross-lane: lane i <- lane i+4 within its 16-lane DPP row (row_shl:4 = 0x104;
// row_shr is the other direction — the R2 bug). bound_ctrl=true: OOB reads 0.
__device__ __forceinline__ float dpp_pull4(float v){
    return __int_as_float(__builtin_amdgcn_update_dpp(0, __float_as_int(v), 0x104, 0xF, 0xF, true));
}

// packed fp32: dual-pipe on CDNA (157.3 TF peak = packed) — halves dot issue count
__device__ __forceinline__ void pk_fma(v2f &a, v2f b, v2f c){
    asm("v_pk_fma_f32 %0, %1, %2, %0" : "+v"(a) : "v"(b), "v"(c));
}
__device__ __forceinline__ v2f pk_mul(v2f b, v2f c){
    v2f d; asm("v_pk_mul_f32 %0, %1, %2" : "=v"(d) : "v"(b), "v"(c)); return d;
}

// Lane roles within each 32-lane row (rr = lane & 31):
//   L0  = {0..7,10,11}        h = rr<8 ? rr : rr-2   owns h0[h] -> LDS slot h
//   L1A = {8,9,16..19,24..27}                        h0-half of L1; owns h1[h] -> LDS slot 16+h
//   L1B = L1A + 4 = {12,13,20..23,28..31}            h1-half of L1 (reads slots 16..25)
//   pad = {14,15}             zero weights, writes trash slot 30
// Combine: L1A lane i pulls partner partial from lane i+4 via dpp row_shl:4.
// Skew: at wave-step s, L0 computes t=s, L1 computes t=s-1.
//
// R5 bug fixed here: hwp/rd were __restrict__ and the ordering pin was
// wave_barrier (IntrNoMem) -> compiler cached the ds_reads across steps and
// the recurrence saw stale h. Fix: no restrict (write/read may-alias keeps
// program order) + asm memory clobber (real compiler fence, zero runtime cost).
// HW side is safe: DS ops of one wave execute in FIFO order.

__device__ __forceinline__ void lstm_step(
    const v2f (&Wp)[4][5], const v2f (&WxP)[4],
    float b0, float b1, float b2, float b3,
    float* hwp, const v2f* rd,
    float &hn, float &c, float xv, float selA,
    float wlin, float blin, int t_l1, float* __restrict__ out, int b)
{
    *hwp = hn;                              // publish prev h (ds_write_b32)
    asm volatile("" ::: "memory");          // compiler fence: reads stay after the write
    const v2f V0=rd[0], V1=rd[1], V2=rd[2], V3=rd[3], V4=rd[4];
    const v2f xx = {xv, xv};

    v2f A0 = pk_mul(Wp[0][0], V0);
    v2f A1 = pk_mul(Wp[1][0], V0);
    v2f A2 = pk_mul(Wp[2][0], V0);
    v2f A3 = pk_mul(Wp[3][0], V0);
    pk_fma(A0, WxP[0], xx); pk_fma(A1, WxP[1], xx); pk_fma(A2, WxP[2], xx); pk_fma(A3, WxP[3], xx);
    pk_fma(A0, Wp[0][1], V1); pk_fma(A1, Wp[1][1], V1); pk_fma(A2, Wp[2][1], V1); pk_fma(A3, Wp[3][1], V1);
    pk_fma(A0, Wp[0][2], V2); pk_fma(A1, Wp[1][2], V2); pk_fma(A2, Wp[2][2], V2); pk_fma(A3, Wp[3][2], V2);
    pk_fma(A0, Wp[0][3], V3); pk_fma(A1, Wp[1][3], V3); pk_fma(A2, Wp[2][3], V3); pk_fma(A3, Wp[3][3], V3);
    pk_fma(A0, Wp[0][4], V4); pk_fma(A1, Wp[1][4], V4); pk_fma(A2, Wp[2][4], V4); pk_fma(A3, Wp[3][4], V4);

    float a0 = A0.x + (A0.y + b0);
    float a1 = A1.x + (A1.y + b1);
    float a2 = A2.x + (A2.y + b2);
    float a3 = A3.x + (A3.y + b3);

    // combine L1 halves: L1A += partner(L1B) partial; others add 0 (selA=0)
    a0 = fmaf(selA, dpp_pull4(a0), a0);
    a1 = fmaf(selA, dpp_pull4(a1), a1);
    a2 = fmaf(selA, dpp_pull4(a2), a2);
    a3 = fmaf(selA, dpp_pull4(a3), a3);

    const float ig = sigm(a0);
    const float fg = sigm(a1);
    const float gg = tanh_(a2);
    const float og = sigm(a3);
    c  = fmaf(fg, c, ig*gg);
    hn = og * tanh_(c);

    if (t_l1 >= T_STEPS-2) {               // uniform branch: true only at s=4095,4096
        float p = hn * wlin;               // wlin!=0 only on L1A lanes
        p += swz<((1<<10)|31)>(p);
        p += swz<((2<<10)|31)>(p);
        p += swz<((4<<10)|31)>(p);
        p += swz<((8<<10)|31)>(p);
        p += swz<((16<<10)|31)>(p);
        if ((threadIdx.x & 31) == 0)
            out[(t_l1 - (T_STEPS-2))*NBATCH + b] = p + blin;
    }
}

// xs[jj] <- lane jj of the row (lane jj holds x[t = 8*i + jj] for this row's batch)
__device__ __forceinline__ void xsplat(float (&xs)[8], float xpre){
    xs[0]=swz<(0<<5)>(xpre); xs[1]=swz<(1<<5)>(xpre); xs[2]=swz<(2<<5)>(xpre); xs[3]=swz<(3<<5)>(xpre);
    xs[4]=swz<(4<<5)>(xpre); xs[5]=swz<(5<<5)>(xpre); xs[6]=swz<(6<<5)>(xpre); xs[7]=swz<(7<<5)>(xpre);
}

__global__ __launch_bounds__(64) void lstm2_kernel(
    const float* __restrict__ x,
    const float* __restrict__ Wih0, const float* __restrict__ Whh0,
    const float* __restrict__ bih0, const float* __restrict__ bhh0,
    const float* __restrict__ Wih1, const float* __restrict__ Whh1,
    const float* __restrict__ bih1, const float* __restrict__ bhh1,
    const float* __restrict__ Wlin, const float* __restrict__ blin_p,
    float* __restrict__ out)
{
    __shared__ float hx[64];                           // 2 rows x 32 floats (slots: 0-9 h0, 16-25 h1, 30 trash)

    const int tid = (int)threadIdx.x;                  // 0..63, two 32-lane rows
    const int rr  = tid & 31;
    const int rbase = tid & 32;                        // row base in hx (0 or 32)
    const int b   = ((int)blockIdx.x * 64 + tid) >> 5; // batch index 0..2047

    const bool isL0  = (rr<8) || rr==10 || rr==11;
    const bool isL1A = rr==8 || rr==9 || (rr>=16&&rr<=19) || (rr>=24&&rr<=27);
    const bool isL1B = rr==12 || rr==13 || (rr>=20&&rr<=23) || (rr>=28&&rr<=31);

    int h = 0;
    if (isL0)       h = (rr<8) ? rr : rr-2;
    else if (isL1A) h = (rr==8||rr==9) ? rr : ((rr<20) ? rr-16 : rr-20);
    else if (isL1B){ const int p = rr-4; h = (p==8||p==9) ? p : ((p<20) ? p-16 : p-20); }

    // LDS publish slot / read base
    const int wslot = isL0 ? h : (isL1A ? 16+h : 30);
    float* hwp = &hx[rbase + wslot];
    const v2f* rd = (const v2f*)&hx[rbase + (isL1B ? 16 : 0)];

    float Wv[4][HID], Wxs[4], bs[4];
    #pragma unroll
    for (int g=0; g<4; ++g){
        const int r = g*HID + h;                                // torch gate order i,f,g,o
        if (isL0){
            #pragma unroll
            for (int j=0;j<HID;++j) Wv[g][j] = Whh0[r*HID+j];
            Wxs[g] = Wih0[r];                                   // W_ih0 is (40,1)
            bs[g] = bih0[r]+bhh0[r];
        } else if (isL1A){
            #pragma unroll
            for (int j=0;j<HID;++j) Wv[g][j] = Wih1[r*HID+j];   // multiplies h0
            Wxs[g] = 0.0f;
            bs[g] = bih1[r]+bhh1[r];
        } else if (isL1B){
            #pragma unroll
            for (int j=0;j<HID;++j) Wv[g][j] = Whh1[r*HID+j];   // multiplies h1
            Wxs[g] = 0.0f;
            bs[g] = 0.0f;                                       // bias lives on L1A
        } else {
            #pragma unroll
            for (int j=0;j<HID;++j) Wv[g][j] = 0.0f;
            Wxs[g] = 0.0f; bs[g] = 0.0f;
        }
    }
    v2f Wp[4][5], WxP[4];
    #pragma unroll
    for (int g=0; g<4; ++g){
        #pragma unroll
        for (int k=0;k<5;++k) Wp[g][k] = v2f{Wv[g][2*k], Wv[g][2*k+1]};
        WxP[g] = v2f{Wxs[g], 0.0f};
    }
    const float selA = isL1A ? 1.0f : 0.0f;
    const float wlin = isL1A ? Wlin[h] : 0.0f;
    const float blin = blin_p[0];

    float hn = 0.0f, c = 0.0f;

    // x prefetch: lane (rr&7) of each row holds x[8*i + (rr&7)] for this row's batch
    const float* xp = x + (size_t)(tid & 7) * NBATCH + b;
    float xpre = xp[0];
    float xs[8];

    // ---- peeled iteration 0 (s = 0..7); L1 gets zero bias at s=0 so its fake
    //      t=-1 step yields h=c=0 exactly (a=0 -> i=f=o=0.5, g=0, c_in=0).
    xsplat(xs, xpre);
    xpre = xp[(size_t)8 * NBATCH];
    lstm_step(Wp,WxP, isL0?bs[0]:0.0f, isL0?bs[1]:0.0f, isL0?bs[2]:0.0f, isL0?bs[3]:0.0f,
              hwp,rd, hn,c, xs[0], selA, wlin, blin, -1, out, b);
    lstm_step(Wp,WxP, bs[0],bs[1],bs[2],bs[3], hwp,rd, hn,c, xs[1], selA, wlin, blin, 0, out, b);
    lstm_step(Wp,WxP, bs[0],bs[1],bs[2],bs[3], hwp,rd, hn,c, xs[2], selA, wlin, blin, 1, out, b);
    lstm_step(Wp,WxP, bs[0],bs[1],bs[2],bs[3], hwp,rd, hn,c, xs[3], selA, wlin, blin, 2, out, b);
    lstm_step(Wp,WxP, bs[0],bs[1],bs[2],bs[3], hwp,rd, hn,c, xs[4], selA, wlin, blin, 3, out, b);
    lstm_step(Wp,WxP, bs[0],bs[1],bs[2],bs[3], hwp,rd, hn,c, xs[5], selA, wlin, blin, 4, out, b);
    lstm_step(Wp,WxP, bs[0],bs[1],bs[2],bs[3], hwp,rd, hn,c, xs[6], selA, wlin, blin, 5, out, b);
    lstm_step(Wp,WxP, bs[0],bs[1],bs[2],bs[3], hwp,rd, hn,c, xs[7], selA, wlin, blin, 6, out, b);

    // ---- main loop: iterations 1..511 (s = 8..4095)
    for (int i=1; i<512; ++i){
        xsplat(xs, xpre);
        if (i < 511) xpre = xp[(size_t)(i+1)*8*NBATCH];   // prefetch next 8 timesteps
        const int s0 = i*8;
        #pragma unroll
        for (int jj=0; jj<8; ++jj){
            lstm_step(Wp,WxP, bs[0],bs[1],bs[2],bs[3], hwp,rd, hn,c, xs[jj],
                      selA, wlin, blin, s0+jj-1, out, b);
        }
    }

    // ---- epilogue wave-step s=4096: L1 computes t=4095 (L0 half computes unused junk, x=0)
    lstm_step(Wp,WxP, bs[0],bs[1],bs[2],bs[3], hwp,rd, hn,c, 0.0f, selA, wlin, blin, T_STEPS-1, out, b);
}

} // anonymous namespace

extern "C" void kernel_launch(void* const* d_in, const int* in_sizes, int n_in,
                              void* d_out, int out_size, void* d_ws, size_t ws_size,
                              hipStream_t stream) {
    const float* x    = (const float*)d_in[0];
    const float* Wih0 = (const float*)d_in[1];
    const float* Whh0 = (const float*)d_in[2];
    const float* bih0 = (const float*)d_in[3];
    const float* bhh0 = (const float*)d_in[4];
    const float* Wih1 = (const float*)d_in[5];
    const float* Whh1 = (const float*)d_in[6];
    const float* bih1 = (const float*)d_in[7];
    const float* bhh1 = (const float*)d_in[8];
    const float* Wlin = (const float*)d_in[9];
    const float* blin = (const float*)d_in[10];
    float* out = (float*)d_out;

    // 2048 batches x 32 lanes = 65536 threads; 64-thread blocks -> 1024 waves (1/SIMD chip-wide)
    hipLaunchKernelGGL(lstm2_kernel, dim3(2048*32/64), dim3(64), 0, stream,
                       x, Wih0, Whh0, bih0, bhh0, Wih1, Whh1, bih1, bhh1, Wlin, blin, out);
}